// Round 1
// baseline (3797.615 us; speedup 1.0000x reference)
//
#include <hip/hip_runtime.h>
#include <hip/hip_bf16.h>
#include <math.h>

// ---------------------------------------------------------------------------
// GAT: 2x GATConv(heads=1) + global mean pool + FC(64->2)
// Pipeline (all fp32):
//   init -> gemm1(+logits) -> edge max -> edge exp/sum -> edge aggregate
//        -> gemm2(input=leaky(h+b1), +logits) -> init -> edge passes
//        -> pool(+b2) -> fc
// ---------------------------------------------------------------------------

__device__ __forceinline__ void atomicMaxF(float* addr, float v) {
    // Bit-trick float atomic max: valid with mixed signs; init value must be -inf.
    if (v >= 0.0f) {
        atomicMax((int*)addr, __float_as_int(v));
    } else {
        atomicMin((unsigned int*)addr, (unsigned int)__float_as_int(v));
    }
}

__device__ __forceinline__ void atomAddF(float* addr, float v) {
    unsafeAtomicAdd(addr, v);   // hw global_atomic_add_f32 on gfx950
}

// --- init: zero hout, pooled, cnt; m=-inf, s=0 ------------------------------
__global__ __launch_bounds__(256) void init_ws(float* __restrict__ hout,
                                               float* __restrict__ m,
                                               float* __restrict__ s,
                                               float* __restrict__ pooled,
                                               float* __restrict__ cnt,
                                               int n, int G) {
    int i = blockIdx.x * 256 + threadIdx.x;
    int n64 = n * 64;
    if (i < n64) hout[i] = 0.0f;
    if (i < n) { m[i] = -__builtin_inff(); s[i] = 0.0f; }
    if (i < G * 64) pooled[i] = 0.0f;
    if (i < G) cnt[i] = 0.0f;
}

// --- node GEMM: h = act(x + bias_in) @ W ; al_s = h.a_src ; al_d = h.a_dst --
template <int IN_DIM>
__global__ __launch_bounds__(256) void node_gemm(const float* __restrict__ x,
                                                 const float* __restrict__ W,
                                                 const float* __restrict__ a_src,
                                                 const float* __restrict__ a_dst,
                                                 const float* __restrict__ bias_in,
                                                 float slope_in,
                                                 float* __restrict__ h,
                                                 float* __restrict__ al_s,
                                                 float* __restrict__ al_d,
                                                 int n) {
    __shared__ float Ws[IN_DIM * 64];
    __shared__ float xs[4][IN_DIM];
    int t = threadIdx.x;
    for (int idx = t; idx < IN_DIM * 64; idx += 256) Ws[idx] = W[idx];
    int wave = t >> 6, lane = t & 63;
    int node = blockIdx.x * 4 + wave;
    if (node < n) {
        for (int d = lane; d < IN_DIM; d += 64) {
            float v = x[(size_t)node * IN_DIM + d];
            if (bias_in) {
                v += bias_in[d];
                v = (v >= 0.0f) ? v : slope_in * v;
            }
            xs[wave][d] = v;
        }
    }
    __syncthreads();
    if (node >= n) return;
    float sum = 0.0f;
#pragma unroll
    for (int d = 0; d < IN_DIM; d++) sum += xs[wave][d] * Ws[d * 64 + lane];
    h[(size_t)node * 64 + lane] = sum;
    float vs = sum * a_src[lane];
    float vd = sum * a_dst[lane];
#pragma unroll
    for (int o = 32; o; o >>= 1) {
        vs += __shfl_xor(vs, o);
        vd += __shfl_xor(vd, o);
    }
    if (lane == 0) { al_s[node] = vs; al_d[node] = vd; }
}

// --- edge pass 1: e = leaky(als[src]+ald[dst], 0.2); segment max ------------
__global__ __launch_bounds__(256) void edge_logit_max(const int* __restrict__ ei,
                                                      int E, int n,
                                                      const float* __restrict__ als,
                                                      const float* __restrict__ ald,
                                                      float* __restrict__ ebuf,
                                                      float* __restrict__ m) {
    int i = blockIdx.x * 256 + threadIdx.x;
    int tot = E + n;
    if (i >= tot) return;
    int s_, d_;
    if (i < E) { s_ = ei[i]; d_ = ei[E + i]; }
    else       { s_ = d_ = i - E; }
    float e = als[s_] + ald[d_];
    e = (e >= 0.0f) ? e : 0.2f * e;
    ebuf[i] = e;
    atomicMaxF(&m[d_], e);
}

// --- edge pass 2: ex = exp(e - m[dst]); segment sum -------------------------
__global__ __launch_bounds__(256) void edge_exp_sum(const int* __restrict__ ei,
                                                    int E, int n,
                                                    float* __restrict__ ebuf,
                                                    const float* __restrict__ m,
                                                    float* __restrict__ ssum) {
    int i = blockIdx.x * 256 + threadIdx.x;
    int tot = E + n;
    if (i >= tot) return;
    int d_ = (i < E) ? ei[E + i] : (i - E);
    float ex = expf(ebuf[i] - m[d_]);
    ebuf[i] = ex;
    atomAddF(&ssum[d_], ex);
}

// --- edge pass 3: hout[dst] += h[src] * (ex / (s[dst]+eps)) -----------------
// 16 lanes per edge, float4 per lane.
__global__ __launch_bounds__(256) void edge_aggregate(const int* __restrict__ ei,
                                                      int E, int n,
                                                      const float* __restrict__ ebuf,
                                                      const float* __restrict__ ssum,
                                                      const float* __restrict__ h,
                                                      float* __restrict__ hout) {
    long long gid = (long long)blockIdx.x * 256 + threadIdx.x;
    int edge = (int)(gid >> 4);
    int lane4 = (int)(gid & 15);
    int tot = E + n;
    if (edge >= tot) return;
    int s_, d_;
    if (edge < E) { s_ = ei[edge]; d_ = ei[E + edge]; }
    else          { s_ = d_ = edge - E; }
    float alpha = ebuf[edge] / (ssum[d_] + 1e-16f);
    const float4 hv = *(const float4*)(h + (size_t)s_ * 64 + lane4 * 4);
    float* outp = hout + (size_t)d_ * 64 + lane4 * 4;
    atomAddF(outp + 0, hv.x * alpha);
    atomAddF(outp + 1, hv.y * alpha);
    atomAddF(outp + 2, hv.z * alpha);
    atomAddF(outp + 3, hv.w * alpha);
}

// --- pooling: pooled[batch[i]] += hout[i] + b2; cnt[batch[i]] += 1 ----------
__global__ __launch_bounds__(256) void pool_kernel(const float* __restrict__ hout,
                                                   const float* __restrict__ b2,
                                                   const int* __restrict__ batch,
                                                   float* __restrict__ pooled,
                                                   float* __restrict__ cnt,
                                                   int n) {
    int t = threadIdx.x;
    int wave = t >> 6, lane = t & 63;
    int node = blockIdx.x * 4 + wave;
    if (node >= n) return;
    int g = batch[node];
    float v = hout[(size_t)node * 64 + lane] + b2[lane];
    atomAddF(&pooled[g * 64 + lane], v);
    if (lane == 0) atomAddF(&cnt[g], 1.0f);
}

// --- final FC: out[g] = (pooled[g]/max(cnt,1)) @ fcW + fcb ------------------
__global__ __launch_bounds__(64) void final_fc(const float* __restrict__ pooled,
                                               const float* __restrict__ cnt,
                                               const float* __restrict__ fcW,
                                               const float* __restrict__ fcb,
                                               float* __restrict__ out) {
    int g = blockIdx.x;
    int lane = threadIdx.x;
    float c = cnt[g];
    c = (c > 1.0f) ? c : 1.0f;
    float p = pooled[g * 64 + lane] / c;
    float s0 = p * fcW[lane * 2 + 0];
    float s1 = p * fcW[lane * 2 + 1];
#pragma unroll
    for (int o = 32; o; o >>= 1) {
        s0 += __shfl_xor(s0, o);
        s1 += __shfl_xor(s1, o);
    }
    if (lane == 0) {
        out[g * 2 + 0] = s0 + fcb[0];
        out[g * 2 + 1] = s1 + fcb[1];
    }
}

extern "C" void kernel_launch(void* const* d_in, const int* in_sizes, int n_in,
                              void* d_out, int out_size, void* d_ws, size_t ws_size,
                              hipStream_t stream) {
    const float* x    = (const float*)d_in[0];
    const int*   ei   = (const int*)d_in[1];
    const int*   batch= (const int*)d_in[2];
    const float* W1   = (const float*)d_in[3];
    const float* as1  = (const float*)d_in[4];
    const float* ad1  = (const float*)d_in[5];
    const float* b1   = (const float*)d_in[6];
    const float* W2   = (const float*)d_in[7];
    const float* as2  = (const float*)d_in[8];
    const float* ad2  = (const float*)d_in[9];
    const float* b2   = (const float*)d_in[10];
    const float* fcW  = (const float*)d_in[11];
    const float* fcb  = (const float*)d_in[12];
    float* out = (float*)d_out;

    const int N = in_sizes[2];       // 100000
    const int E = in_sizes[1] / 2;   // 1600000
    const int G = out_size / 2;      // 256
    const int tot = E + N;

    float* ws     = (float*)d_ws;
    float* bufH   = ws;                         // N*64  (gemm output h)
    float* bufO   = bufH + (size_t)N * 64;      // N*64  (aggregated output)
    float* als    = bufO + (size_t)N * 64;      // N
    float* ald    = als + N;                    // N
    float* m      = ald + N;                    // N
    float* ssum   = m + N;                      // N
    float* ebuf   = ssum + N;                   // E+N
    float* pooled = ebuf + tot;                 // G*64
    float* cnt    = pooled + (size_t)G * 64;    // G

    dim3 b256(256);
    int gInit = (N * 64 + 255) / 256;
    int gNode = (N + 3) / 4;
    int gEdge = (tot + 255) / 256;
    int gAgg  = (int)(((long long)tot * 16 + 255) / 256);

    // ---- layer 1 ----
    init_ws<<<gInit, b256, 0, stream>>>(bufO, m, ssum, pooled, cnt, N, G);
    node_gemm<72><<<gNode, b256, 0, stream>>>(x, W1, as1, ad1, nullptr, 0.0f,
                                              bufH, als, ald, N);
    edge_logit_max<<<gEdge, b256, 0, stream>>>(ei, E, N, als, ald, ebuf, m);
    edge_exp_sum<<<gEdge, b256, 0, stream>>>(ei, E, N, ebuf, m, ssum);
    edge_aggregate<<<gAgg, b256, 0, stream>>>(ei, E, N, ebuf, ssum, bufH, bufO);

    // ---- layer 2 (input = leaky(bufO + b1, 0.01)) ----
    node_gemm<64><<<gNode, b256, 0, stream>>>(bufO, W2, as2, ad2, b1, 0.01f,
                                              bufH, als, ald, N);
    init_ws<<<gInit, b256, 0, stream>>>(bufO, m, ssum, pooled, cnt, N, G);
    edge_logit_max<<<gEdge, b256, 0, stream>>>(ei, E, N, als, ald, ebuf, m);
    edge_exp_sum<<<gEdge, b256, 0, stream>>>(ei, E, N, ebuf, m, ssum);
    edge_aggregate<<<gAgg, b256, 0, stream>>>(ei, E, N, ebuf, ssum, bufH, bufO);

    // ---- pool + fc ----
    pool_kernel<<<gNode, b256, 0, stream>>>(bufO, b2, batch, pooled, cnt, N);
    final_fc<<<G, 64, 0, stream>>>(pooled, cnt, fcW, fcb, out);
}

// Round 2
// 905.897 us; speedup vs baseline: 4.1921x; 4.1921x over previous
//
#include <hip/hip_runtime.h>
#include <hip/hip_bf16.h>
#include <math.h>

// ---------------------------------------------------------------------------
// GAT: 2x GATConv(heads=1) + global mean pool + FC(64->2)
// R1 rewrite: CSR-gather aggregation (zero feature atomics).
//   init -> hist(deg) -> scan(rowptr,cursor,selfloop) -> scatter(srcs)
//   -> gemm1(+logits) -> aggregate_csr -> gemm2(+b1,leaky,+logits)
//   -> aggregate_csr -> pool(run-length) -> fc
// CSR build depends only on edge_index: built once, used by both layers.
// ---------------------------------------------------------------------------

__device__ __forceinline__ void atomAddF(float* a, float v) {
    unsafeAtomicAdd(a, v);   // hw global_atomic_add_f32 on gfx950
}

// --- init: deg=1 (self loop), pooled=0, cnt=0 -------------------------------
__global__ __launch_bounds__(256) void init_all(int* __restrict__ deg,
                                                float* __restrict__ pooled,
                                                float* __restrict__ cnt,
                                                int n, int G) {
    int i = blockIdx.x * 256 + threadIdx.x;
    if (i < n) deg[i] = 1;             // every node gets a self-loop
    if (i < G * 64) pooled[i] = 0.0f;
    if (i < G) cnt[i] = 0.0f;
}

// --- histogram of incoming-edge counts --------------------------------------
__global__ __launch_bounds__(256) void hist_deg(const int* __restrict__ ei,
                                                int E, int* __restrict__ deg) {
    int i = blockIdx.x * 256 + threadIdx.x;
    if (i >= E) return;
    atomicAdd(&deg[ei[E + i]], 1);
}

// --- exclusive scan -> rowptr; place self-loop at slot 0; deg becomes cursor -
__global__ __launch_bounds__(1024) void scan_rowptr(int* __restrict__ deg,
                                                    int* __restrict__ rowptr,
                                                    int* __restrict__ srcs,
                                                    int n, int tot) {
    __shared__ int sums[1024];
    int t = threadIdx.x;
    int chunk = (n + 1023) >> 10;
    int beg = t * chunk;
    int end = min(beg + chunk, n);
    int s = 0;
    for (int i = beg; i < end; i++) s += deg[i];
    sums[t] = s;
    __syncthreads();
    if (t == 0) {
        int acc = 0;
        for (int i = 0; i < 1024; i++) { int v = sums[i]; sums[i] = acc; acc += v; }
    }
    __syncthreads();
    int run = sums[t];
    for (int i = beg; i < end; i++) {
        int d = deg[i];
        rowptr[i] = run;
        srcs[run] = i;        // self-loop occupies slot 0 of each segment
        deg[i] = run + 1;     // reuse deg[] as scatter cursor
        run += d;
    }
    if (t == 0) rowptr[n] = tot;
}

// --- scatter real edges into CSR --------------------------------------------
__global__ __launch_bounds__(256) void scatter_edges(const int* __restrict__ ei,
                                                     int E,
                                                     int* __restrict__ cursor,
                                                     int* __restrict__ srcs) {
    int i = blockIdx.x * 256 + threadIdx.x;
    if (i >= E) return;
    int s = ei[i];
    int d = ei[E + i];
    int pos = atomicAdd(&cursor[d], 1);
    srcs[pos] = s;
}

// --- node GEMM: h = act(x + bias_in) @ W ; al_s = h.a_src ; al_d = h.a_dst --
template <int IN_DIM>
__global__ __launch_bounds__(256) void node_gemm(const float* __restrict__ x,
                                                 const float* __restrict__ W,
                                                 const float* __restrict__ a_src,
                                                 const float* __restrict__ a_dst,
                                                 const float* __restrict__ bias_in,
                                                 float slope_in,
                                                 float* __restrict__ h,
                                                 float* __restrict__ al_s,
                                                 float* __restrict__ al_d,
                                                 int n) {
    __shared__ float Ws[IN_DIM * 64];
    __shared__ float xs[4][IN_DIM];
    int t = threadIdx.x;
    for (int idx = t; idx < IN_DIM * 64; idx += 256) Ws[idx] = W[idx];
    int wave = t >> 6, lane = t & 63;
    int node = blockIdx.x * 4 + wave;
    if (node < n) {
        for (int d = lane; d < IN_DIM; d += 64) {
            float v = x[(size_t)node * IN_DIM + d];
            if (bias_in) {
                v += bias_in[d];
                v = (v >= 0.0f) ? v : slope_in * v;
            }
            xs[wave][d] = v;
        }
    }
    __syncthreads();
    if (node >= n) return;
    float sum = 0.0f;
#pragma unroll
    for (int d = 0; d < IN_DIM; d++) sum += xs[wave][d] * Ws[d * 64 + lane];
    h[(size_t)node * 64 + lane] = sum;
    float vs = sum * a_src[lane];
    float vd = sum * a_dst[lane];
#pragma unroll
    for (int o = 32; o; o >>= 1) {
        vs += __shfl_xor(vs, o);
        vd += __shfl_xor(vd, o);
    }
    if (lane == 0) { al_s[node] = vs; al_d[node] = vd; }
}

// --- CSR aggregate: segment softmax + weighted gather, 16 lanes / node ------
__global__ __launch_bounds__(256) void gat_aggregate(const int* __restrict__ rowptr,
                                                     const int* __restrict__ srcs,
                                                     const float* __restrict__ als,
                                                     const float* __restrict__ ald,
                                                     const float* __restrict__ h,
                                                     float* __restrict__ hout,
                                                     int n) {
    int t = threadIdx.x;
    int sub = t >> 4, lane = t & 15;
    int node = blockIdx.x * 16 + sub;
    if (node >= n) return;
    int beg = rowptr[node], end = rowptr[node + 1];
    float aldv = ald[node];

    // pass 1: segment max (lanes parallel over edges)
    float mx = -__builtin_inff();
    for (int j = beg + lane; j < end; j += 16) {
        float e = als[srcs[j]] + aldv;
        e = (e >= 0.0f) ? e : 0.2f * e;
        mx = fmaxf(mx, e);
    }
#pragma unroll
    for (int o = 8; o; o >>= 1) mx = fmaxf(mx, __shfl_xor(mx, o));

    // pass 2: sum of exp
    float sm = 0.0f;
    for (int j = beg + lane; j < end; j += 16) {
        float e = als[srcs[j]] + aldv;
        e = (e >= 0.0f) ? e : 0.2f * e;
        sm += expf(e - mx);
    }
#pragma unroll
    for (int o = 8; o; o >>= 1) sm += __shfl_xor(sm, o);
    float inv = 1.0f / (sm + 1e-16f);

    // pass 3: weighted feature gather (lanes over features, float4 each)
    float4 acc = make_float4(0.0f, 0.0f, 0.0f, 0.0f);
    for (int j = beg; j < end; j++) {
        int s = srcs[j];
        float e = als[s] + aldv;
        e = (e >= 0.0f) ? e : 0.2f * e;
        float w = expf(e - mx) * inv;
        const float4 hv = *(const float4*)(h + (size_t)s * 64 + lane * 4);
        acc.x += w * hv.x;
        acc.y += w * hv.y;
        acc.z += w * hv.z;
        acc.w += w * hv.w;
    }
    *(float4*)(hout + (size_t)node * 64 + lane * 4) = acc;
}

// --- pooling: run-length accumulate over sorted batch, then one atomic ------
__global__ __launch_bounds__(256) void pool_run(const float* __restrict__ hout,
                                                const float* __restrict__ b2,
                                                const int* __restrict__ batch,
                                                float* __restrict__ pooled,
                                                float* __restrict__ cnt,
                                                int n) {
    int t = threadIdx.x;
    int wv = blockIdx.x * 4 + (t >> 6);
    int lane = t & 63;
    int start = wv * 64;
    if (start >= n) return;
    int end = min(start + 64, n);
    float bb = b2[lane];
    int gcur = batch[start];
    float acc = 0.0f;
    int rl = 0;
    for (int node = start; node < end; node++) {
        int g = batch[node];
        if (g != gcur) {
            atomAddF(&pooled[gcur * 64 + lane], acc);
            if (lane == 0) atomAddF(&cnt[gcur], (float)rl);
            acc = 0.0f; rl = 0; gcur = g;
        }
        acc += hout[(size_t)node * 64 + lane] + bb;
        rl++;
    }
    atomAddF(&pooled[gcur * 64 + lane], acc);
    if (lane == 0) atomAddF(&cnt[gcur], (float)rl);
}

// --- final FC: out[g] = (pooled[g]/max(cnt,1)) @ fcW + fcb ------------------
__global__ __launch_bounds__(64) void final_fc(const float* __restrict__ pooled,
                                               const float* __restrict__ cnt,
                                               const float* __restrict__ fcW,
                                               const float* __restrict__ fcb,
                                               float* __restrict__ out) {
    int g = blockIdx.x;
    int lane = threadIdx.x;
    float c = cnt[g];
    c = (c > 1.0f) ? c : 1.0f;
    float p = pooled[g * 64 + lane] / c;
    float s0 = p * fcW[lane * 2 + 0];
    float s1 = p * fcW[lane * 2 + 1];
#pragma unroll
    for (int o = 32; o; o >>= 1) {
        s0 += __shfl_xor(s0, o);
        s1 += __shfl_xor(s1, o);
    }
    if (lane == 0) {
        out[g * 2 + 0] = s0 + fcb[0];
        out[g * 2 + 1] = s1 + fcb[1];
    }
}

extern "C" void kernel_launch(void* const* d_in, const int* in_sizes, int n_in,
                              void* d_out, int out_size, void* d_ws, size_t ws_size,
                              hipStream_t stream) {
    const float* x    = (const float*)d_in[0];
    const int*   ei   = (const int*)d_in[1];
    const int*   batch= (const int*)d_in[2];
    const float* W1   = (const float*)d_in[3];
    const float* as1  = (const float*)d_in[4];
    const float* ad1  = (const float*)d_in[5];
    const float* b1   = (const float*)d_in[6];
    const float* W2   = (const float*)d_in[7];
    const float* as2  = (const float*)d_in[8];
    const float* ad2  = (const float*)d_in[9];
    const float* b2   = (const float*)d_in[10];
    const float* fcW  = (const float*)d_in[11];
    const float* fcb  = (const float*)d_in[12];
    float* out = (float*)d_out;

    const int N = in_sizes[2];       // 100000
    const int E = in_sizes[1] / 2;   // 1600000
    const int G = out_size / 2;      // 256
    const int tot = E + N;

    float* ws     = (float*)d_ws;
    float* bufH   = ws;                          // N*64
    float* bufO   = bufH + (size_t)N * 64;       // N*64
    float* als    = bufO + (size_t)N * 64;       // N
    float* ald    = als + N;                     // N
    float* pooled = ald + N;                     // G*64
    float* cnt    = pooled + (size_t)G * 64;     // G
    int*   deg    = (int*)(cnt + G);             // N  (becomes cursor)
    int*   rowptr = deg + N;                     // N+1
    int*   srcs   = rowptr + N + 1;              // E+N

    dim3 b256(256);
    int gN    = (N + 255) / 256;
    int gE    = (E + 255) / 256;
    int gNode = (N + 3) / 4;
    int gAgg  = (N + 15) / 16;
    int gPool = ((N + 63) / 64 + 3) / 4;

    // ---- CSR build (edge_index only — shared by both layers) ----
    init_all<<<gN, b256, 0, stream>>>(deg, pooled, cnt, N, G);
    hist_deg<<<gE, b256, 0, stream>>>(ei, E, deg);
    scan_rowptr<<<1, 1024, 0, stream>>>(deg, rowptr, srcs, N, tot);
    scatter_edges<<<gE, b256, 0, stream>>>(ei, E, deg, srcs);

    // ---- layer 1 ----
    node_gemm<72><<<gNode, b256, 0, stream>>>(x, W1, as1, ad1, nullptr, 0.0f,
                                              bufH, als, ald, N);
    gat_aggregate<<<gAgg, b256, 0, stream>>>(rowptr, srcs, als, ald, bufH, bufO, N);

    // ---- layer 2 (input = leaky(bufO + b1, 0.01)) ----
    node_gemm<64><<<gNode, b256, 0, stream>>>(bufO, W2, as2, ad2, b1, 0.01f,
                                              bufH, als, ald, N);
    gat_aggregate<<<gAgg, b256, 0, stream>>>(rowptr, srcs, als, ald, bufH, bufO, N);

    // ---- pool + fc ----
    pool_run<<<gPool, b256, 0, stream>>>(bufO, b2, batch, pooled, cnt, N);
    final_fc<<<G, 64, 0, stream>>>(pooled, cnt, fcW, fcb, out);
}

// Round 3
// 610.556 us; speedup vs baseline: 6.2199x; 1.4837x over previous
//
#include <hip/hip_runtime.h>
#include <hip/hip_bf16.h>
#include <math.h>

// ---------------------------------------------------------------------------
// GAT: 2x GATConv(heads=1) + global mean pool + FC(64->2)
// R2: parallel 3-phase CSR rowptr scan (was: single-block serial scan, 310us).
//   init -> hist(deg) -> scan_p1/p2/p3 -> scatter(srcs)
//   -> gemm1(+logits) -> aggregate_csr -> gemm2(+b1,leaky,+logits)
//   -> aggregate_csr -> pool(run-length) -> fc
// ---------------------------------------------------------------------------

#define SCAN_T 256
#define SCAN_I 4
#define SCAN_IPB (SCAN_T * SCAN_I)   // 1024 nodes per block

__device__ __forceinline__ void atomAddF(float* a, float v) {
    unsafeAtomicAdd(a, v);   // hw global_atomic_add_f32 on gfx950
}

// --- init: deg=1 (self loop), pooled=0, cnt=0 -------------------------------
__global__ __launch_bounds__(256) void init_all(int* __restrict__ deg,
                                                float* __restrict__ pooled,
                                                float* __restrict__ cnt,
                                                int n, int G) {
    int i = blockIdx.x * 256 + threadIdx.x;
    if (i < n) deg[i] = 1;             // every node gets a self-loop
    if (i < G * 64) pooled[i] = 0.0f;
    if (i < G) cnt[i] = 0.0f;
}

// --- histogram of incoming-edge counts --------------------------------------
__global__ __launch_bounds__(256) void hist_deg(const int* __restrict__ ei,
                                                int E, int* __restrict__ deg) {
    int i = blockIdx.x * 256 + threadIdx.x;
    if (i >= E) return;
    atomicAdd(&deg[ei[E + i]], 1);
}

// --- scan phase 1: per-block degree sums ------------------------------------
__global__ __launch_bounds__(SCAN_T) void scan_p1(const int* __restrict__ deg,
                                                  int* __restrict__ bsums, int n) {
    int b = blockIdx.x, t = threadIdx.x;
    int base = b * SCAN_IPB + t * SCAN_I;
    int s = 0;
#pragma unroll
    for (int k = 0; k < SCAN_I; k++) {
        int i = base + k;
        if (i < n) s += deg[i];
    }
    __shared__ int red[SCAN_T];
    red[t] = s;
    __syncthreads();
    for (int o = SCAN_T / 2; o; o >>= 1) {
        if (t < o) red[t] += red[t + o];
        __syncthreads();
    }
    if (t == 0) bsums[b] = red[0];
}

// --- scan phase 2: exclusive scan of block sums (B <= 256) ------------------
__global__ __launch_bounds__(256) void scan_p2(int* __restrict__ bsums, int B) {
    __shared__ int tmp[256];
    int t = threadIdx.x;
    int v = (t < B) ? bsums[t] : 0;
    tmp[t] = v;
    __syncthreads();
    for (int o = 1; o < 256; o <<= 1) {
        int u = (t >= o) ? tmp[t - o] : 0;
        __syncthreads();
        tmp[t] += u;
        __syncthreads();
    }
    if (t < B) bsums[t] = tmp[t] - v;   // exclusive
}

// --- scan phase 3: write rowptr, self-loop srcs, cursor ---------------------
__global__ __launch_bounds__(SCAN_T) void scan_p3(int* __restrict__ deg,
                                                  const int* __restrict__ bsums,
                                                  int* __restrict__ rowptr,
                                                  int* __restrict__ srcs,
                                                  int n, int tot) {
    int b = blockIdx.x, t = threadIdx.x;
    int base = b * SCAN_IPB + t * SCAN_I;
    int d[SCAN_I];
    int s = 0;
#pragma unroll
    for (int k = 0; k < SCAN_I; k++) {
        int i = base + k;
        d[k] = (i < n) ? deg[i] : 0;
        s += d[k];
    }
    __shared__ int tmp[SCAN_T];
    tmp[t] = s;
    __syncthreads();
    for (int o = 1; o < SCAN_T; o <<= 1) {
        int u = (t >= o) ? tmp[t - o] : 0;
        __syncthreads();
        tmp[t] += u;
        __syncthreads();
    }
    int run = bsums[b] + tmp[t] - s;    // exclusive offset for this thread
#pragma unroll
    for (int k = 0; k < SCAN_I; k++) {
        int i = base + k;
        if (i >= n) break;
        rowptr[i] = run;
        srcs[run] = i;      // self-loop at slot 0 of segment
        deg[i] = run + 1;   // deg[] becomes scatter cursor
        run += d[k];
    }
    if (b == 0 && t == 0) rowptr[n] = tot;
}

// --- scatter real edges into CSR --------------------------------------------
__global__ __launch_bounds__(256) void scatter_edges(const int* __restrict__ ei,
                                                     int E,
                                                     int* __restrict__ cursor,
                                                     int* __restrict__ srcs) {
    int i = blockIdx.x * 256 + threadIdx.x;
    if (i >= E) return;
    int s = ei[i];
    int d = ei[E + i];
    int pos = atomicAdd(&cursor[d], 1);
    srcs[pos] = s;
}

// --- node GEMM: h = act(x + bias_in) @ W ; al_s = h.a_src ; al_d = h.a_dst --
template <int IN_DIM>
__global__ __launch_bounds__(256) void node_gemm(const float* __restrict__ x,
                                                 const float* __restrict__ W,
                                                 const float* __restrict__ a_src,
                                                 const float* __restrict__ a_dst,
                                                 const float* __restrict__ bias_in,
                                                 float slope_in,
                                                 float* __restrict__ h,
                                                 float* __restrict__ al_s,
                                                 float* __restrict__ al_d,
                                                 int n) {
    __shared__ float Ws[IN_DIM * 64];
    __shared__ float xs[4][IN_DIM];
    int t = threadIdx.x;
    for (int idx = t; idx < IN_DIM * 64; idx += 256) Ws[idx] = W[idx];
    int wave = t >> 6, lane = t & 63;
    int node = blockIdx.x * 4 + wave;
    if (node < n) {
        for (int d = lane; d < IN_DIM; d += 64) {
            float v = x[(size_t)node * IN_DIM + d];
            if (bias_in) {
                v += bias_in[d];
                v = (v >= 0.0f) ? v : slope_in * v;
            }
            xs[wave][d] = v;
        }
    }
    __syncthreads();
    if (node >= n) return;
    float sum = 0.0f;
#pragma unroll
    for (int d = 0; d < IN_DIM; d++) sum += xs[wave][d] * Ws[d * 64 + lane];
    h[(size_t)node * 64 + lane] = sum;
    float vs = sum * a_src[lane];
    float vd = sum * a_dst[lane];
#pragma unroll
    for (int o = 32; o; o >>= 1) {
        vs += __shfl_xor(vs, o);
        vd += __shfl_xor(vd, o);
    }
    if (lane == 0) { al_s[node] = vs; al_d[node] = vd; }
}

// --- CSR aggregate: segment softmax + weighted gather, 16 lanes / node ------
__global__ __launch_bounds__(256) void gat_aggregate(const int* __restrict__ rowptr,
                                                     const int* __restrict__ srcs,
                                                     const float* __restrict__ als,
                                                     const float* __restrict__ ald,
                                                     const float* __restrict__ h,
                                                     float* __restrict__ hout,
                                                     int n) {
    int t = threadIdx.x;
    int sub = t >> 4, lane = t & 15;
    int node = blockIdx.x * 16 + sub;
    if (node >= n) return;
    int beg = rowptr[node], end = rowptr[node + 1];
    float aldv = ald[node];

    // pass 1: segment max (lanes parallel over edges)
    float mx = -__builtin_inff();
    for (int j = beg + lane; j < end; j += 16) {
        float e = als[srcs[j]] + aldv;
        e = (e >= 0.0f) ? e : 0.2f * e;
        mx = fmaxf(mx, e);
    }
#pragma unroll
    for (int o = 8; o; o >>= 1) mx = fmaxf(mx, __shfl_xor(mx, o));

    // pass 2: sum of exp
    float sm = 0.0f;
    for (int j = beg + lane; j < end; j += 16) {
        float e = als[srcs[j]] + aldv;
        e = (e >= 0.0f) ? e : 0.2f * e;
        sm += expf(e - mx);
    }
#pragma unroll
    for (int o = 8; o; o >>= 1) sm += __shfl_xor(sm, o);
    float inv = 1.0f / (sm + 1e-16f);

    // pass 3: weighted feature gather (lanes over features, float4 each)
    float4 acc = make_float4(0.0f, 0.0f, 0.0f, 0.0f);
    for (int j = beg; j < end; j++) {
        int s = srcs[j];
        float e = als[s] + aldv;
        e = (e >= 0.0f) ? e : 0.2f * e;
        float w = expf(e - mx) * inv;
        const float4 hv = *(const float4*)(h + (size_t)s * 64 + lane * 4);
        acc.x += w * hv.x;
        acc.y += w * hv.y;
        acc.z += w * hv.z;
        acc.w += w * hv.w;
    }
    *(float4*)(hout + (size_t)node * 64 + lane * 4) = acc;
}

// --- pooling: run-length accumulate over sorted batch, then one atomic ------
__global__ __launch_bounds__(256) void pool_run(const float* __restrict__ hout,
                                                const float* __restrict__ b2,
                                                const int* __restrict__ batch,
                                                float* __restrict__ pooled,
                                                float* __restrict__ cnt,
                                                int n) {
    int t = threadIdx.x;
    int wv = blockIdx.x * 4 + (t >> 6);
    int lane = t & 63;
    int start = wv * 64;
    if (start >= n) return;
    int end = min(start + 64, n);
    float bb = b2[lane];
    int gcur = batch[start];
    float acc = 0.0f;
    int rl = 0;
    for (int node = start; node < end; node++) {
        int g = batch[node];
        if (g != gcur) {
            atomAddF(&pooled[gcur * 64 + lane], acc);
            if (lane == 0) atomAddF(&cnt[gcur], (float)rl);
            acc = 0.0f; rl = 0; gcur = g;
        }
        acc += hout[(size_t)node * 64 + lane] + bb;
        rl++;
    }
    atomAddF(&pooled[gcur * 64 + lane], acc);
    if (lane == 0) atomAddF(&cnt[gcur], (float)rl);
}

// --- final FC: out[g] = (pooled[g]/max(cnt,1)) @ fcW + fcb ------------------
__global__ __launch_bounds__(64) void final_fc(const float* __restrict__ pooled,
                                               const float* __restrict__ cnt,
                                               const float* __restrict__ fcW,
                                               const float* __restrict__ fcb,
                                               float* __restrict__ out) {
    int g = blockIdx.x;
    int lane = threadIdx.x;
    float c = cnt[g];
    c = (c > 1.0f) ? c : 1.0f;
    float p = pooled[g * 64 + lane] / c;
    float s0 = p * fcW[lane * 2 + 0];
    float s1 = p * fcW[lane * 2 + 1];
#pragma unroll
    for (int o = 32; o; o >>= 1) {
        s0 += __shfl_xor(s0, o);
        s1 += __shfl_xor(s1, o);
    }
    if (lane == 0) {
        out[g * 2 + 0] = s0 + fcb[0];
        out[g * 2 + 1] = s1 + fcb[1];
    }
}

extern "C" void kernel_launch(void* const* d_in, const int* in_sizes, int n_in,
                              void* d_out, int out_size, void* d_ws, size_t ws_size,
                              hipStream_t stream) {
    const float* x    = (const float*)d_in[0];
    const int*   ei   = (const int*)d_in[1];
    const int*   batch= (const int*)d_in[2];
    const float* W1   = (const float*)d_in[3];
    const float* as1  = (const float*)d_in[4];
    const float* ad1  = (const float*)d_in[5];
    const float* b1   = (const float*)d_in[6];
    const float* W2   = (const float*)d_in[7];
    const float* as2  = (const float*)d_in[8];
    const float* ad2  = (const float*)d_in[9];
    const float* b2   = (const float*)d_in[10];
    const float* fcW  = (const float*)d_in[11];
    const float* fcb  = (const float*)d_in[12];
    float* out = (float*)d_out;

    const int N = in_sizes[2];       // 100000
    const int E = in_sizes[1] / 2;   // 1600000
    const int G = out_size / 2;      // 256
    const int tot = E + N;
    const int B = (N + SCAN_IPB - 1) / SCAN_IPB;   // scan blocks (98 for 100K)

    float* ws     = (float*)d_ws;
    float* bufH   = ws;                          // N*64
    float* bufO   = bufH + (size_t)N * 64;       // N*64
    float* als    = bufO + (size_t)N * 64;       // N
    float* ald    = als + N;                     // N
    float* pooled = ald + N;                     // G*64
    float* cnt    = pooled + (size_t)G * 64;     // G
    int*   deg    = (int*)(cnt + G);             // N  (becomes cursor)
    int*   rowptr = deg + N;                     // N+1
    int*   srcs   = rowptr + N + 1;              // E+N
    int*   bsums  = srcs + tot;                  // B

    dim3 b256(256);
    int gN    = (N + 255) / 256;
    int gE    = (E + 255) / 256;
    int gNode = (N + 3) / 4;
    int gAgg  = (N + 15) / 16;
    int gPool = ((N + 63) / 64 + 3) / 4;

    // ---- CSR build (edge_index only — shared by both layers) ----
    init_all<<<gN, b256, 0, stream>>>(deg, pooled, cnt, N, G);
    hist_deg<<<gE, b256, 0, stream>>>(ei, E, deg);
    scan_p1<<<B, SCAN_T, 0, stream>>>(deg, bsums, N);
    scan_p2<<<1, 256, 0, stream>>>(bsums, B);
    scan_p3<<<B, SCAN_T, 0, stream>>>(deg, bsums, rowptr, srcs, N, tot);
    scatter_edges<<<gE, b256, 0, stream>>>(ei, E, deg, srcs);

    // ---- layer 1 ----
    node_gemm<72><<<gNode, b256, 0, stream>>>(x, W1, as1, ad1, nullptr, 0.0f,
                                              bufH, als, ald, N);
    gat_aggregate<<<gAgg, b256, 0, stream>>>(rowptr, srcs, als, ald, bufH, bufO, N);

    // ---- layer 2 (input = leaky(bufO + b1, 0.01)) ----
    node_gemm<64><<<gNode, b256, 0, stream>>>(bufO, W2, as2, ad2, b1, 0.01f,
                                              bufH, als, ald, N);
    gat_aggregate<<<gAgg, b256, 0, stream>>>(rowptr, srcs, als, ald, bufH, bufO, N);

    // ---- pool + fc ----
    pool_run<<<gPool, b256, 0, stream>>>(bufO, b2, batch, pooled, cnt, N);
    final_fc<<<G, 64, 0, stream>>>(pooled, cnt, fcW, fcb, out);
}